// Round 2
// baseline (632.043 us; speedup 1.0000x reference)
//
#include <hip/hip_runtime.h>

typedef unsigned short u16;
typedef unsigned int u32;
typedef float f32x4 __attribute__((ext_vector_type(4)));
typedef __bf16 bf16x8 __attribute__((ext_vector_type(8)));

__device__ __forceinline__ u16 f2bf(float f) {
  u32 b = __float_as_uint(f);
  b += 0x7fffu + ((b >> 16) & 1u);
  return (u16)(b >> 16);
}

__device__ __forceinline__ void gload16(const void* g, void* l) {
  __builtin_amdgcn_global_load_lds(
      (const __attribute__((address_space(1))) void*)g,
      (__attribute__((address_space(3))) void*)l, 16, 0, 0);
}

// ---------------- f32 -> bf16 convert ----------------
__global__ __launch_bounds__(256)
void cvt_f32_bf16(const float4* __restrict__ in, ushort4* __restrict__ out, int n4) {
  int i = blockIdx.x * blockDim.x + threadIdx.x;
  int stride = gridDim.x * blockDim.x;
  for (; i < n4; i += stride) {
    float4 v = in[i];
    ushort4 o;
    o.x = f2bf(v.x); o.y = f2bf(v.y); o.z = f2bf(v.z); o.w = f2bf(v.w);
    out[i] = o;
  }
}

// ---------------- bf16 B^T GEMM: C[m,n] = sum_k A[m,k]*B[n,k] ----------------
// A [M,K] bf16 row-major, B [N,K] bf16 row-major. 128x128 tile, BK=32,
// 256 thr = 4 waves (2x2), 4x4 16x16x32 fragments per wave. M,N,K multiples of 128/128/32.
template<bool BF16OUT>
__global__ __launch_bounds__(256)
void gemm_bt(const u16* __restrict__ A, const u16* __restrict__ B,
             u16* __restrict__ Cb, float* __restrict__ Cf,
             const float* __restrict__ bias, int N, int K)
{
  __shared__ u16 As[128 * 32];
  __shared__ u16 Bs[128 * 32];
  const int tid = threadIdx.x;
  const int lane = tid & 63;
  const int wid = tid >> 6;
  const int wr = (wid >> 1) * 64;
  const int wc = (wid & 1) * 64;
  const int row0 = blockIdx.y * 128;
  const int col0 = blockIdx.x * 128;
  const int rlo = lane & 15, g4 = lane >> 4;

  f32x4 acc[4][4] = {};

  const int u0 = wid * 64 + lane;
  const int nk = K >> 5;
  for (int kt = 0; kt < nk; ++kt) {
    __syncthreads();  // prev tile fully consumed
    #pragma unroll
    for (int i = 0; i < 2; ++i) {
      int u = u0 + i * 256;                       // 16B-unit index, 512 units = 8KB
      const u16* ga = A + (size_t)(row0 + (u >> 2)) * K + kt * 32 + (u & 3) * 8;
      gload16(ga, &As[(wid * 64 + i * 256) * 8]); // wave-uniform LDS base + lane*16
      const u16* gb = B + (size_t)(col0 + (u >> 2)) * K + kt * 32 + (u & 3) * 8;
      gload16(gb, &Bs[(wid * 64 + i * 256) * 8]);
    }
    __syncthreads();  // compiler drains vmcnt before barrier
    bf16x8 a[4], b[4];
    #pragma unroll
    for (int m = 0; m < 4; ++m)
      a[m] = *(const bf16x8*)&As[(wr + m * 16 + rlo) * 32 + g4 * 8];
    #pragma unroll
    for (int nn = 0; nn < 4; ++nn)
      b[nn] = *(const bf16x8*)&Bs[(wc + nn * 16 + rlo) * 32 + g4 * 8];
    #pragma unroll
    for (int m = 0; m < 4; ++m)
      #pragma unroll
      for (int nn = 0; nn < 4; ++nn)
        acc[m][nn] = __builtin_amdgcn_mfma_f32_16x16x32_bf16(a[m], b[nn], acc[m][nn], 0, 0, 0);
  }
  // epilogue: C/D layout col=lane&15, row=(lane>>4)*4+v (verified m89/m91)
  #pragma unroll
  for (int m = 0; m < 4; ++m) {
    #pragma unroll
    for (int nn = 0; nn < 4; ++nn) {
      int row = row0 + wr + m * 16 + g4 * 4;
      int col = col0 + wc + nn * 16 + rlo;
      #pragma unroll
      for (int v = 0; v < 4; ++v) {
        if (BF16OUT) {
          Cb[(size_t)(row + v) * N + col] = f2bf(acc[m][nn][v]);
        } else {
          Cf[(size_t)(row + v) * N + col] = acc[m][nn][v] + bias[col];
        }
      }
    }
  }
}

// ---------------- attention: one wave per (partition, head) ----------------
// kv [50176,1536] bf16 (cols 0..767 = K, 768..1535 = V). Q==K (reference bug).
// S = Kh*Kh^T*0.125, softmax over k (cols, 49 valid), O = P*Vh -> out bf16 [50176,768].
__global__ __launch_bounds__(64)
void attn_part(const u16* __restrict__ kv, const int* __restrict__ ids,
               u16* __restrict__ out)
{
  __shared__ u16 Ksw[64 * 64];   // K tile, XOR-swizzled; reused for P
  __shared__ u16 Vt[64 * 64];    // V^T tile [d][k], XOR-swizzled
  __shared__ int rowg[64];
  const int lane = threadIdx.x;
  const int p = blockIdx.x / 12;
  const int h = blockIdx.x - p * 12;
  const int n = p >> 5;                 // L = 1568 = 32*49 partitions per sample
  const int lbase = (p & 31) * 49;

  if (lane < 49) rowg[lane] = n * 1568 + ids[n * 1568 + lbase + lane];
  __syncthreads();

  const int rr8 = lane >> 3, c16 = lane & 7;   // 8 rows x 8 x 16B chunks
  // stage K rows (gathered), swizzle 16B slot ^= row&7; zero-pad rows 49..63
  #pragma unroll
  for (int it = 0; it < 8; ++it) {
    int r = it * 8 + rr8;
    uint4 val = {0, 0, 0, 0};
    if (r < 49) val = *(const uint4*)(kv + (size_t)rowg[r] * 1536 + h * 64 + c16 * 8);
    *(uint4*)&Ksw[r * 64 + ((c16 ^ (r & 7)) * 8)] = val;
  }
  // stage V transposed: Vt[d][k], same slot swizzle on d-rows; zero-pad k>=49
  #pragma unroll
  for (int it = 0; it < 8; ++it) {
    int r = it * 8 + rr8;
    uint4 val = {0, 0, 0, 0};
    if (r < 49) val = *(const uint4*)(kv + (size_t)rowg[r] * 1536 + 768 + h * 64 + c16 * 8);
    const u16* vs = (const u16*)&val;
    #pragma unroll
    for (int j = 0; j < 8; ++j) {
      int d = c16 * 8 + j;
      Vt[d * 64 + (((r >> 3) ^ (d & 7)) * 8) + (r & 7)] = vs[j];
    }
  }
  __syncthreads();

  const int rlo = lane & 15, g4 = lane >> 4;
  // K fragments: row = m*16+rlo, k-chunk slot = (g*4+g4)^(row&7)
  bf16x8 af[4][2];
  #pragma unroll
  for (int m = 0; m < 4; ++m)
    #pragma unroll
    for (int g = 0; g < 2; ++g) {
      int row = m * 16 + rlo;
      af[m][g] = *(const bf16x8*)&Ksw[row * 64 + (((g * 4 + g4) ^ (row & 7)) * 8)];
    }
  // S = K*K^T : same fragments serve as A and B (q = k bug)
  f32x4 s[4][4] = {};
  #pragma unroll
  for (int m = 0; m < 4; ++m)
    #pragma unroll
    for (int nf = 0; nf < 4; ++nf)
      #pragma unroll
      for (int g = 0; g < 2; ++g)
        s[m][nf] = __builtin_amdgcn_mfma_f32_16x16x32_bf16(af[m][g], af[nf][g], s[m][nf], 0, 0, 0);

  // softmax over k. Lane holds rows 16m+4*g4+v, cols 16nf+rlo -> a full row lives
  // in one 16-lane group; reduce with shfl_xor 1/2/4/8. Mask cols >= 49.
  #pragma unroll
  for (int m = 0; m < 4; ++m) {
    #pragma unroll
    for (int v = 0; v < 4; ++v) {
      float mx = -1e30f;
      #pragma unroll
      for (int nf = 0; nf < 4; ++nf) {
        float x = s[m][nf][v] * 0.125f;
        int col = nf * 16 + rlo;
        x = (col < 49) ? x : -1e30f;
        s[m][nf][v] = x;
        mx = fmaxf(mx, x);
      }
      #pragma unroll
      for (int d = 1; d < 16; d <<= 1) mx = fmaxf(mx, __shfl_xor(mx, d));
      float sum = 0.f;
      #pragma unroll
      for (int nf = 0; nf < 4; ++nf) {
        int col = nf * 16 + rlo;
        float e = (col < 49) ? __expf(s[m][nf][v] - mx) : 0.f;
        s[m][nf][v] = e;
        sum += e;
      }
      #pragma unroll
      for (int d = 1; d < 16; d <<= 1) sum += __shfl_xor(sum, d);
      float inv = 1.0f / sum;
      #pragma unroll
      for (int nf = 0; nf < 4; ++nf) s[m][nf][v] *= inv;
    }
  }

  __syncthreads();
  // write P (bf16) into Ksw buffer, same swizzle scheme (scalar writes)
  #pragma unroll
  for (int m = 0; m < 4; ++m)
    #pragma unroll
    for (int nf = 0; nf < 4; ++nf)
      #pragma unroll
      for (int v = 0; v < 4; ++v) {
        int R = m * 16 + g4 * 4 + v;
        int C = nf * 16 + rlo;
        Ksw[R * 64 + (((C >> 3) ^ (R & 7)) * 8) + (C & 7)] = f2bf(s[m][nf][v]);
      }
  __syncthreads();

  // O = P * V : A-frags from P (rows q), B-frags from Vt (rows d) — both contiguous b128
  bf16x8 pa[4][2], vb[4][2];
  #pragma unroll
  for (int m = 0; m < 4; ++m)
    #pragma unroll
    for (int g = 0; g < 2; ++g) {
      int row = m * 16 + rlo;
      pa[m][g] = *(const bf16x8*)&Ksw[row * 64 + (((g * 4 + g4) ^ (row & 7)) * 8)];
    }
  #pragma unroll
  for (int nd = 0; nd < 4; ++nd)
    #pragma unroll
    for (int g = 0; g < 2; ++g) {
      int row = nd * 16 + rlo;
      vb[nd][g] = *(const bf16x8*)&Vt[row * 64 + (((g * 4 + g4) ^ (row & 7)) * 8)];
    }
  f32x4 o[4][4] = {};
  #pragma unroll
  for (int m = 0; m < 4; ++m)
    #pragma unroll
    for (int nd = 0; nd < 4; ++nd)
      #pragma unroll
      for (int g = 0; g < 2; ++g)
        o[m][nd] = __builtin_amdgcn_mfma_f32_16x16x32_bf16(pa[m][g], vb[nd][g], o[m][nd], 0, 0, 0);

  // store valid rows q<49: out[(p*49+q)*768 + h*64 + d]
  #pragma unroll
  for (int m = 0; m < 4; ++m)
    #pragma unroll
    for (int nd = 0; nd < 4; ++nd)
      #pragma unroll
      for (int v = 0; v < 4; ++v) {
        int q = m * 16 + g4 * 4 + v;
        if (q < 49) {
          size_t token = (size_t)p * 49 + q;
          out[token * 768 + h * 64 + nd * 16 + rlo] = f2bf(o[m][nd][v]);
        }
      }
}

// ---------------- launch ----------------
extern "C" void kernel_launch(void* const* d_in, const int* in_sizes, int n_in,
                              void* d_out, int out_size, void* d_ws, size_t ws_size,
                              hipStream_t stream) {
  const float* x      = (const float*)d_in[0];   // [32,1568,768]
  const float* w_qkv  = (const float*)d_in[1];   // [2304,768]
  const float* w_proj = (const float*)d_in[2];   // [768,768]
  const float* b_proj = (const float*)d_in[3];   // [768]
  const int*   ids    = (const int*)d_in[4];     // [32,1568]
  float* outp = (float*)d_out;

  char* ws = (char*)d_ws;
  u16* kvbuf = (u16*)ws;                                   // 154,140,672 B : kv bf16 [50176,1536]
  u16* xbuf  = (u16*)(ws + 154140672);                     //  77,070,336 B : x bf16, later attn_out bf16
  u16* wkv   = (u16*)(ws + 154140672 + 77070336);          //   2,359,296 B : w_qkv rows 768..2303 bf16
  u16* wproj = (u16*)(ws + 154140672 + 77070336 + 2359296);//   1,179,648 B

  auto cgrid = [](int n4) { int g = (n4 + 255) / 256; return g > 2048 ? 2048 : g; };

  // convert inputs to bf16 (only K/V rows of w_qkv — q is dead per reference bug)
  cvt_f32_bf16<<<cgrid(9633792), 256, 0, stream>>>((const float4*)x, (ushort4*)xbuf, 9633792);
  cvt_f32_bf16<<<cgrid(294912), 256, 0, stream>>>((const float4*)(w_qkv + 768 * 768), (ushort4*)wkv, 294912);
  cvt_f32_bf16<<<cgrid(147456), 256, 0, stream>>>((const float4*)w_proj, (ushort4*)wproj, 147456);

  // kv = x @ w_kv^T  : M=50176, N=1536, K=768
  dim3 g1(12, 392);
  gemm_bt<true><<<g1, 256, 0, stream>>>(xbuf, wkv, kvbuf, nullptr, nullptr, 1536, 768);

  // attention (1024 partitions x 12 heads), writes attn_out into xbuf
  attn_part<<<12288, 64, 0, stream>>>(kvbuf, ids, xbuf);

  // out = attn_out @ w_proj^T + b : M=50176, N=768, K=768
  dim3 g2(6, 392);
  gemm_bt<false><<<g2, 256, 0, stream>>>(xbuf, wproj, nullptr, outp, b_proj, 768, 768);
}

// Round 5
// 574.400 us; speedup vs baseline: 1.1004x; 1.1004x over previous
//
#include <hip/hip_runtime.h>

typedef unsigned short u16;
typedef unsigned int u32;
typedef float f32x4 __attribute__((ext_vector_type(4)));
typedef __bf16 bf16x8 __attribute__((ext_vector_type(8)));

__device__ __forceinline__ u16 f2bf(float f) {
  u32 b = __float_as_uint(f);
  b += 0x7fffu + ((b >> 16) & 1u);
  return (u16)(b >> 16);
}

__device__ __forceinline__ void gload16(const void* g, void* l) {
  __builtin_amdgcn_global_load_lds(
      (const __attribute__((address_space(1))) void*)g,
      (__attribute__((address_space(3))) void*)l, 16, 0, 0);
}

// bijective XCD-aware block swizzle (m204 variant; works for nwg%8 != 0)
__device__ __forceinline__ int xcd_swz(int wgid, int nwg) {
  const int q = nwg >> 3, r = nwg & 7;
  const int xcd = wgid & 7, pos = wgid >> 3;
  return (xcd < r ? xcd * (q + 1) : r * (q + 1) + (xcd - r) * q) + pos;
}

// ---------------- f32 -> bf16 convert ----------------
__global__ __launch_bounds__(256)
void cvt_f32_bf16(const float4* __restrict__ in, ushort4* __restrict__ out, int n4) {
  int i = blockIdx.x * blockDim.x + threadIdx.x;
  int stride = gridDim.x * blockDim.x;
  for (; i < n4; i += stride) {
    float4 v = in[i];
    ushort4 o;
    o.x = f2bf(v.x); o.y = f2bf(v.y); o.z = f2bf(v.z); o.w = f2bf(v.w);
    out[i] = o;
  }
}

// ---------------- 256x256 8-phase bf16 B^T GEMM ----------------
// C[m,n] = sum_k A[m,k]*B[n,k].  A [M,K], B [N,K] bf16 row-major.
// BM=BN=256, BK=64, 512 thr = 8 waves (2Mx4N). LDS 128 KiB (2 buf x (A+B)).
// Pipeline discipline (race fix vs r3):
//   - prologue: stage 7 half-tiles, vmcnt(6), s_barrier  -> tile0 landed for ALL waves
//   - per iter: ONE vmcnt(6) at phase-3 end BEFORE closing barrier -> h<=4t+7
//     landed for all waves when iter t+1 reads (cross-wave completion via barrier)
//   - read-phases (0,2): lgkmcnt(0) between the two barriers -> every wave's
//     ds_reads drained before it passes the closing barrier, so next-phase
//     stage-writes can never overtake a pending read
// Half order per K-tile: [B0,B1,A0,A1] (h = 4t+0..3). Swizzle: byte col ^=
// ((r>>1)&7)<<4 -> 2-way-free ds_read_b128; inverse applied on global source.
template<bool BF16OUT>
__global__ __launch_bounds__(512, 2)
void gemm256(const u16* __restrict__ A, const u16* __restrict__ B,
             u16* __restrict__ Cb, float* __restrict__ Cf,
             const float* __restrict__ bias, int N, int K, int gx)
{
  __shared__ u16 LDS[2][4][8192];   // [buf][A0,A1,B0,B1][128 rows x 64 el]
  const int tid = threadIdx.x;
  const int lane = tid & 63;
  const int wid = tid >> 6;
  const int wm = wid >> 2, wn = wid & 3;       // 2 x 4 wave grid
  const int rlo = lane & 15, g4 = lane >> 4;

  const int id = xcd_swz(blockIdx.x, gridDim.x);
  const int by = id / gx, bx = id - by * gx;
  const int row0 = by * 256, col0 = bx * 256;
  const int nk = K >> 6;

  // staging geometry (per thread, per half-tile: 2 x 16B)
  const int sr = tid >> 3;                     // row 0..63 (+64 for i=1)
  const int c_phys = (tid & 7) * 16;           // linear LDS byte col in row

  auto stage = [&](int h) {
    int kt = h >> 2; if (kt > nk - 1) kt = nk - 1;   // tail clamp (writes dead/idempotent)
    const int type = h & 3;                          // 0=B0 1=B1 2=A0 3=A1
    const u16* src = (type < 2) ? B : A;
    const int rbase = ((type < 2) ? col0 : row0) + (type & 1) * 128;
    const int slot = (type < 2) ? (2 + (type & 1)) : (type - 2);
    const int buf = (h >> 2) & 1;                    // parity of UNCLAMPED k-tile
    #pragma unroll
    for (int i = 0; i < 2; ++i) {
      int r = sr + i * 64;
      int c_log = c_phys ^ (((r >> 1) & 7) << 4);    // inverse swizzle on source
      const u16* g = src + (size_t)(rbase + r) * K + kt * 64 + (c_log >> 1);
      gload16(g, &LDS[buf][slot][wid * 512 + i * 4096]);  // uniform base + lane*16
    }
  };
  auto ldA = [&](int buf, int m8, int ks) -> bf16x8 {
    int row = wm * 128 + m8 * 16 + rlo;          // 0..255
    int r = row & 127;
    int col = (ks * 32 + g4 * 8) ^ (((r >> 1) & 7) << 3);   // elements
    return *(const bf16x8*)&LDS[buf][row >> 7][r * 64 + col];
  };
  auto ldB = [&](int buf, int n, int ks) -> bf16x8 {
    int row = wn * 64 + n * 16 + rlo;            // 0..255
    int r = row & 127;
    int col = (ks * 32 + g4 * 8) ^ (((r >> 1) & 7) << 3);
    return *(const bf16x8*)&LDS[buf][2 + (row >> 7)][r * 64 + col];
  };

  f32x4 acc[8][4] = {};
  bf16x8 bf[4][2], af[4][2];

  // prologue: stage 7 half-tiles (K0 complete + K1 B0,B1,A0), then SYNC:
  // own-wave vmcnt(6) -> own h0..h3 landed; barrier -> ALL waves' h0..h3 landed.
  #pragma unroll
  for (int h = 0; h < 7; ++h) stage(h);
  asm volatile("s_waitcnt vmcnt(6)" ::: "memory");
  __builtin_amdgcn_s_barrier();

  for (int t = 0; t < nk; ++t) {
    const int buf = t & 1;
    // ---- phase 0: reads B-all + A-lo; MFMA quadrant (0,0) ----
    #pragma unroll
    for (int n = 0; n < 4; ++n)
      #pragma unroll
      for (int ks = 0; ks < 2; ++ks) bf[n][ks] = ldB(buf, n, ks);
    #pragma unroll
    for (int m = 0; m < 4; ++m)
      #pragma unroll
      for (int ks = 0; ks < 2; ++ks) af[m][ks] = ldA(buf, m, ks);
    stage(4 * t + 7);                                  // (t+1).A1 -> other buf
    __builtin_amdgcn_s_barrier();
    asm volatile("s_waitcnt lgkmcnt(0)" ::: "memory"); // drain ALL ds_reads (incl bf[2],bf[3])
    __builtin_amdgcn_s_setprio(1);
    #pragma unroll
    for (int m = 0; m < 4; ++m)
      #pragma unroll
      for (int ks = 0; ks < 2; ++ks) {
        acc[m][0] = __builtin_amdgcn_mfma_f32_16x16x32_bf16(af[m][ks], bf[0][ks], acc[m][0], 0, 0, 0);
        acc[m][1] = __builtin_amdgcn_mfma_f32_16x16x32_bf16(af[m][ks], bf[1][ks], acc[m][1], 0, 0, 0);
      }
    __builtin_amdgcn_s_setprio(0);
    __builtin_amdgcn_s_barrier();
    // ---- phase 1: regs only; MFMA quadrant (0,1) ----
    stage(4 * t + 8);                                  // (t+2).B0 -> cur buf (readers drained ph0)
    __builtin_amdgcn_s_barrier();
    __builtin_amdgcn_s_setprio(1);
    #pragma unroll
    for (int m = 0; m < 4; ++m)
      #pragma unroll
      for (int ks = 0; ks < 2; ++ks) {
        acc[m][2] = __builtin_amdgcn_mfma_f32_16x16x32_bf16(af[m][ks], bf[2][ks], acc[m][2], 0, 0, 0);
        acc[m][3] = __builtin_amdgcn_mfma_f32_16x16x32_bf16(af[m][ks], bf[3][ks], acc[m][3], 0, 0, 0);
      }
    __builtin_amdgcn_s_setprio(0);
    __builtin_amdgcn_s_barrier();
    // ---- phase 2: reads A-hi; MFMA quadrant (1,0) ----
    #pragma unroll
    for (int m = 0; m < 4; ++m)
      #pragma unroll
      for (int ks = 0; ks < 2; ++ks) af[m][ks] = ldA(buf, 4 + m, ks);
    stage(4 * t + 9);                                  // (t+2).B1 -> cur buf (readers drained ph0)
    __builtin_amdgcn_s_barrier();
    asm volatile("s_waitcnt lgkmcnt(0)" ::: "memory");
    __builtin_amdgcn_s_setprio(1);
    #pragma unroll
    for (int m = 0; m < 4; ++m)
      #pragma unroll
      for (int ks = 0; ks < 2; ++ks) {
        acc[4 + m][0] = __builtin_amdgcn_mfma_f32_16x16x32_bf16(af[m][ks], bf[0][ks], acc[4 + m][0], 0, 0, 0);
        acc[4 + m][1] = __builtin_amdgcn_mfma_f32_16x16x32_bf16(af[m][ks], bf[1][ks], acc[4 + m][1], 0, 0, 0);
      }
    __builtin_amdgcn_s_setprio(0);
    __builtin_amdgcn_s_barrier();
    // ---- phase 3: regs only; MFMA quadrant (1,1); per-tile vmcnt BEFORE closing barrier ----
    stage(4 * t + 10);                                 // (t+2).A0 -> cur buf (readers drained ph2)
    __builtin_amdgcn_s_barrier();
    __builtin_amdgcn_s_setprio(1);
    #pragma unroll
    for (int m = 0; m < 4; ++m)
      #pragma unroll
      for (int ks = 0; ks < 2; ++ks) {
        acc[4 + m][2] = __builtin_amdgcn_mfma_f32_16x16x32_bf16(af[m][ks], bf[2][ks], acc[4 + m][2], 0, 0, 0);
        acc[4 + m][3] = __builtin_amdgcn_mfma_f32_16x16x32_bf16(af[m][ks], bf[3][ks], acc[4 + m][3], 0, 0, 0);
      }
    __builtin_amdgcn_s_setprio(0);
    // outstanding = h 4t+4..4t+10 (14 loads); leave 6 -> h<=4t+7 landed.
    // barrier AFTER the wait => all waves' tile-(t+1) data landed before next reads.
    asm volatile("s_waitcnt vmcnt(6)" ::: "memory");
    __builtin_amdgcn_s_barrier();
  }

  // epilogue: C/D layout col=lane&15, row=(lane>>4)*4+v
  #pragma unroll
  for (int m = 0; m < 8; ++m) {
    #pragma unroll
    for (int n = 0; n < 4; ++n) {
      int row = row0 + wm * 128 + m * 16 + g4 * 4;
      int col = col0 + wn * 64 + n * 16 + rlo;
      #pragma unroll
      for (int v = 0; v < 4; ++v) {
        if (BF16OUT) {
          Cb[(size_t)(row + v) * N + col] = f2bf(acc[m][n][v]);
        } else {
          Cf[(size_t)(row + v) * N + col] = acc[m][n][v] + bias[col];
        }
      }
    }
  }
}

// ---------------- attention: one wave per (partition, head) ----------------
// kv [50176,1536] bf16 (cols 0..767 = K, 768..1535 = V). Q==K (reference bug).
// S = Kh*Kh^T*0.125, softmax over k (cols, 49 valid), O = P*Vh -> out bf16 [50176,768].
__global__ __launch_bounds__(64)
void attn_part(const u16* __restrict__ kv, const int* __restrict__ ids,
               u16* __restrict__ out)
{
  __shared__ u16 Ksw[64 * 64];   // K tile, XOR-swizzled; reused for P
  __shared__ u16 Vt[64 * 64];    // V^T tile [d][k], XOR-swizzled
  __shared__ int rowg[64];
  const int lane = threadIdx.x;
  const int p = blockIdx.x / 12;
  const int h = blockIdx.x - p * 12;
  const int n = p >> 5;                 // L = 1568 = 32*49 partitions per sample
  const int lbase = (p & 31) * 49;

  if (lane < 49) rowg[lane] = n * 1568 + ids[n * 1568 + lbase + lane];
  __syncthreads();

  const int rr8 = lane >> 3, c16 = lane & 7;   // 8 rows x 8 x 16B chunks
  #pragma unroll
  for (int it = 0; it < 8; ++it) {
    int r = it * 8 + rr8;
    uint4 val = {0, 0, 0, 0};
    if (r < 49) val = *(const uint4*)(kv + (size_t)rowg[r] * 1536 + h * 64 + c16 * 8);
    *(uint4*)&Ksw[r * 64 + ((c16 ^ (r & 7)) * 8)] = val;
  }
  #pragma unroll
  for (int it = 0; it < 8; ++it) {
    int r = it * 8 + rr8;
    uint4 val = {0, 0, 0, 0};
    if (r < 49) val = *(const uint4*)(kv + (size_t)rowg[r] * 1536 + 768 + h * 64 + c16 * 8);
    const u16* vs = (const u16*)&val;
    #pragma unroll
    for (int j = 0; j < 8; ++j) {
      int d = c16 * 8 + j;
      Vt[d * 64 + (((r >> 3) ^ (d & 7)) * 8) + (r & 7)] = vs[j];
    }
  }
  __syncthreads();

  const int rlo = lane & 15, g4 = lane >> 4;
  bf16x8 af[4][2];
  #pragma unroll
  for (int m = 0; m < 4; ++m)
    #pragma unroll
    for (int g = 0; g < 2; ++g) {
      int row = m * 16 + rlo;
      af[m][g] = *(const bf16x8*)&Ksw[row * 64 + (((g * 4 + g4) ^ (row & 7)) * 8)];
    }
  f32x4 s[4][4] = {};
  #pragma unroll
  for (int m = 0; m < 4; ++m)
    #pragma unroll
    for (int nf = 0; nf < 4; ++nf)
      #pragma unroll
      for (int g = 0; g < 2; ++g)
        s[m][nf] = __builtin_amdgcn_mfma_f32_16x16x32_bf16(af[m][g], af[nf][g], s[m][nf], 0, 0, 0);

  #pragma unroll
  for (int m = 0; m < 4; ++m) {
    #pragma unroll
    for (int v = 0; v < 4; ++v) {
      float mx = -1e30f;
      #pragma unroll
      for (int nf = 0; nf < 4; ++nf) {
        float x = s[m][nf][v] * 0.125f;
        int col = nf * 16 + rlo;
        x = (col < 49) ? x : -1e30f;
        s[m][nf][v] = x;
        mx = fmaxf(mx, x);
      }
      #pragma unroll
      for (int d = 1; d < 16; d <<= 1) mx = fmaxf(mx, __shfl_xor(mx, d));
      float sum = 0.f;
      #pragma unroll
      for (int nf = 0; nf < 4; ++nf) {
        int col = nf * 16 + rlo;
        float e = (col < 49) ? __expf(s[m][nf][v] - mx) : 0.f;
        s[m][nf][v] = e;
        sum += e;
      }
      #pragma unroll
      for (int d = 1; d < 16; d <<= 1) sum += __shfl_xor(sum, d);
      float inv = 1.0f / sum;
      #pragma unroll
      for (int nf = 0; nf < 4; ++nf) s[m][nf][v] *= inv;
    }
  }

  __syncthreads();
  #pragma unroll
  for (int m = 0; m < 4; ++m)
    #pragma unroll
    for (int nf = 0; nf < 4; ++nf)
      #pragma unroll
      for (int v = 0; v < 4; ++v) {
        int R = m * 16 + g4 * 4 + v;
        int C = nf * 16 + rlo;
        Ksw[R * 64 + (((C >> 3) ^ (R & 7)) * 8) + (C & 7)] = f2bf(s[m][nf][v]);
      }
  __syncthreads();

  bf16x8 pa[4][2], vb[4][2];
  #pragma unroll
  for (int m = 0; m < 4; ++m)
    #pragma unroll
    for (int g = 0; g < 2; ++g) {
      int row = m * 16 + rlo;
      pa[m][g] = *(const bf16x8*)&Ksw[row * 64 + (((g * 4 + g4) ^ (row & 7)) * 8)];
    }
  #pragma unroll
  for (int nd = 0; nd < 4; ++nd)
    #pragma unroll
    for (int g = 0; g < 2; ++g) {
      int row = nd * 16 + rlo;
      vb[nd][g] = *(const bf16x8*)&Vt[row * 64 + (((g * 4 + g4) ^ (row & 7)) * 8)];
    }
  f32x4 o[4][4] = {};
  #pragma unroll
  for (int m = 0; m < 4; ++m)
    #pragma unroll
    for (int nd = 0; nd < 4; ++nd)
      #pragma unroll
      for (int g = 0; g < 2; ++g)
        o[m][nd] = __builtin_amdgcn_mfma_f32_16x16x32_bf16(pa[m][g], vb[nd][g], o[m][nd], 0, 0, 0);

  #pragma unroll
  for (int m = 0; m < 4; ++m)
    #pragma unroll
    for (int nd = 0; nd < 4; ++nd)
      #pragma unroll
      for (int v = 0; v < 4; ++v) {
        int q = m * 16 + g4 * 4 + v;
        if (q < 49) {
          size_t token = (size_t)p * 49 + q;
          out[token * 768 + h * 64 + nd * 16 + rlo] = f2bf(o[m][nd][v]);
        }
      }
}

// ---------------- launch ----------------
extern "C" void kernel_launch(void* const* d_in, const int* in_sizes, int n_in,
                              void* d_out, int out_size, void* d_ws, size_t ws_size,
                              hipStream_t stream) {
  const float* x      = (const float*)d_in[0];   // [32,1568,768]
  const float* w_qkv  = (const float*)d_in[1];   // [2304,768]
  const float* w_proj = (const float*)d_in[2];   // [768,768]
  const float* b_proj = (const float*)d_in[3];   // [768]
  const int*   ids    = (const int*)d_in[4];     // [32,1568]
  float* outp = (float*)d_out;

  char* ws = (char*)d_ws;
  u16* kvbuf = (u16*)ws;                                   // 154,140,672 B : kv bf16 [50176,1536]
  u16* xbuf  = (u16*)(ws + 154140672);                     //  77,070,336 B : x bf16, later attn_out bf16
  u16* wkv   = (u16*)(ws + 154140672 + 77070336);          //   2,359,296 B : w_qkv rows 768..2303 bf16
  u16* wproj = (u16*)(ws + 154140672 + 77070336 + 2359296);//   1,179,648 B

  auto cgrid = [](int n4) { int g = (n4 + 255) / 256; return g > 2048 ? 2048 : g; };

  cvt_f32_bf16<<<cgrid(9633792), 256, 0, stream>>>((const float4*)x, (ushort4*)xbuf, 9633792);
  cvt_f32_bf16<<<cgrid(294912), 256, 0, stream>>>((const float4*)(w_qkv + 768 * 768), (ushort4*)wkv, 294912);
  cvt_f32_bf16<<<cgrid(147456), 256, 0, stream>>>((const float4*)w_proj, (ushort4*)wproj, 147456);

  // kv = x @ w_kv^T : M=50176, N=1536, K=768 -> grid 6x196
  gemm256<true><<<dim3(6 * 196), 512, 0, stream>>>(xbuf, wkv, kvbuf, nullptr, nullptr, 1536, 768, 6);

  // attention (1024 partitions x 12 heads), writes attn_out into xbuf
  attn_part<<<12288, 64, 0, stream>>>(kvbuf, ids, xbuf);

  // out = attn_out @ w_proj^T + b : M=50176, N=768, K=768 -> grid 3x196
  gemm256<false><<<dim3(3 * 196), 512, 0, stream>>>(xbuf, wproj, nullptr, outp, b_proj, 768, 768, 3);
}